// Round 4
// baseline (382.274 us; speedup 1.0000x reference)
//
#include <hip/hip_runtime.h>

typedef unsigned short u16;
typedef _Float16 f16;
typedef f16    f16x8  __attribute__((ext_vector_type(8)));
typedef float  f32x4  __attribute__((ext_vector_type(4)));
typedef u16    u16x4  __attribute__((ext_vector_type(4)));
typedef u16    u16x8  __attribute__((ext_vector_type(8)));

#define MFMA16(a, b, c) __builtin_amdgcn_mfma_f32_16x16x32_f16(a, b, c, 0, 0, 0)

template <int V> struct ic { static constexpr int v = V; };

// fp32 -> fp16 RNE (v_cvt_f16_f32), bit pattern as u16
__device__ __forceinline__ u16 f2h(float f) {
    f16 h = (f16)f;
    return __builtin_bit_cast(u16, h);
}

// pack two fp32 -> fp16x2 in one u32 (2x v_cvt_f16_f32 + v_pack_b32_f16)
__device__ __forceinline__ unsigned pkh(float a, float b) {
    union { f16 h[2]; unsigned u; } c;
    c.h[0] = (f16)a;
    c.h[1] = (f16)b;
    return c.u;
}

// async global->LDS, 16B per lane; LDS dest is wave-uniform base + lane*16
__device__ __forceinline__ void gll16(const void* g, void* l) {
    __builtin_amdgcn_global_load_lds((__attribute__((address_space(1))) void*)(void*)(g),
                                     (__attribute__((address_space(3))) void*)(l), 16, 0, 0);
}

// ------------- fused prep: weight casts fp32->fp16 + RMSNorm ----------------
// blocks [0,4096): RMSNorm rows; [4096, 4096+16384): weight cast chunks
__global__ __launch_bounds__(256) void prep_k(const float* __restrict__ x,
                                              const float* __restrict__ w,
                                              u16* __restrict__ xn,
                                              const float* __restrict__ wq,
                                              u16* __restrict__ oq,
                                              const float* __restrict__ wo,
                                              u16* __restrict__ oo) {
    const int bid = blockIdx.x;
    if (bid >= 4096) {
        const int cb = bid - 4096;
        const float* in;
        u16* out;
        size_t i;
        if (cb < 12288) { in = wq; out = oq; i = ((size_t)cb * 256 + threadIdx.x) * 4; }
        else            { in = wo; out = oo; i = ((size_t)(cb - 12288) * 256 + threadIdx.x) * 4; }
        float4 v = *(const float4*)(in + i);
        u16x4 o;
        o.x = f2h(v.x); o.y = f2h(v.y); o.z = f2h(v.z); o.w = f2h(v.w);
        *(u16x4*)(out + i) = o;
        return;
    }
    const int row = bid;
    const float* xr = x + (size_t)row * 2048;
    const int base = threadIdx.x * 8;
    float4 v0 = *(const float4*)(xr + base);
    float4 v1 = *(const float4*)(xr + base + 4);
    float ss = v0.x * v0.x + v0.y * v0.y + v0.z * v0.z + v0.w * v0.w +
               v1.x * v1.x + v1.y * v1.y + v1.z * v1.z + v1.w * v1.w;
#pragma unroll
    for (int off = 32; off >= 1; off >>= 1) ss += __shfl_xor(ss, off);
    __shared__ float red[4];
    const int wave = threadIdx.x >> 6, lane = threadIdx.x & 63;
    if (lane == 0) red[wave] = ss;
    __syncthreads();
    float tot = red[0] + red[1] + red[2] + red[3];
    float sc = rsqrtf(tot * (1.0f / 2048.0f) + 1e-6f);
    const float* wp = w + base;
    u16x4 a, b;
    a.x = f2h(v0.x * sc * wp[0]); a.y = f2h(v0.y * sc * wp[1]);
    a.z = f2h(v0.z * sc * wp[2]); a.w = f2h(v0.w * sc * wp[3]);
    b.x = f2h(v1.x * sc * wp[4]); b.y = f2h(v1.y * sc * wp[5]);
    b.z = f2h(v1.z * sc * wp[6]); b.w = f2h(v1.w * sc * wp[7]);
    u16* o = xn + (size_t)row * 2048 + base;
    *(u16x4*)(o)     = a;
    *(u16x4*)(o + 4) = b;
}

// ------- deep-pipe GEMM: 128x256 tile, single barrier per K-tile ------------
// C = A[M,K] * B[N,K]^T, fp16 in. 512 threads = 8 waves (2M x 4N), per-wave
// 64x64 (acc[4][4]). BK=32, quad-buffered LDS 4 x 24KB = 96KB, 1 block/CU.
// KEY CHANGE vs R2 (which tied 134us of the 2-barrier structure): fragments
// for tile t+1 are ds_read into registers right AFTER barrier(t) and complete
// UNDER tile t's 16 MFMAs -> LDS reads overlap the matrix pipe; ONE barrier
// per K-tile. Safety: at barrier(t) every wave finished MFMA(t-1) which
// lgkm-consumed its buf(t-1) frag reads; stage(t+3) (overwriting buf t-1 mod4)
// issues only after barrier(t). Frag reads of buf t+1 come after the barrier
// that follows all waves' own vmcnt gates (cross-wave staging visible).
// Gate accounting: in-flight at gate(t) = tiles {t+1,t+2} (3 loads each);
// vmcnt(3) drains t+1; tail t=NT-2 -> vmcnt(0).
// Swizzle identical to verified kernels (granule p^((r>>1)&3), gsrc, fofs).
// EPI 0: q/k/v via per-wave XOR-swizzled [64][64] restage (verified R2).
// EPI 1: fp32 row-major C[M,N] direct.
template <int EPI>
__global__ __launch_bounds__(512, 2) void gemm_dp(const u16* __restrict__ A,
                                                  const u16* __restrict__ B,
                                                  int K, int N,
                                                  float* __restrict__ Cf,
                                                  u16* __restrict__ q,
                                                  u16* __restrict__ kk,
                                                  u16* __restrict__ vt) {
    __shared__ __align__(16) u16 lds_[49152];   // 96KB: buf b at b*12288; A [0,4096) B [4096,12288)
    const int tid = threadIdx.x;
    const int wave = tid >> 6, lane = tid & 63;
    const int wm = wave >> 2, wn = wave & 3;
    const int quad = lane >> 4, l16 = lane & 15;

    const int bid = blockIdx.x;
    const int xcd = bid & 7, ci = bid >> 3;
    int bm, bn;
    if (EPI == 0) { bm = ci & 31; bn = xcd * 3 + (ci >> 5); }   // 32 x 24 grid, 768 blocks
    else          { bm = ci;      bn = xcd; }                   // 32 x 8 grid, 256 blocks
    const int m0 = bm * 128, n0 = bn * 256;

    // ---- staging: 512 threads; rows tid>>2, granule-permuted source --------
    const int gsrc = (tid & 3) ^ ((tid >> 3) & 3);
    const u16* Ag = A + (size_t)(m0 + (tid >> 2)) * K + gsrc * 8;
    const u16* Bg = B + (size_t)(n0 + (tid >> 2)) * K + gsrc * 8;
    u16* ldsW = lds_ + wave * 512;

    auto stage = [&](int t) {                    // 3 loads: A, B-lo, B-hi
        u16* d = ldsW + (t & 3) * 12288;
        const u16* ga = Ag + t * 32;
        const u16* gb = Bg + t * 32;
        gll16(ga, d);
        gll16(gb, d + 4096);
        gll16(gb + (size_t)128 * K, d + 8192);
    };

    // ---- fragment read offsets (u16 units) ----
    const int fofs = (quad ^ ((l16 >> 1) & 3)) * 8;
    const int aOff = (wm * 64 + l16) * 32 + fofs;
    const int bOff = 4096 + (wn * 64 + l16) * 32 + fofs;

    auto ldfrag = [&](int t, f16x8 (&fa)[4], f16x8 (&fb)[4]) {
        const u16* buf = lds_ + (t & 3) * 12288;
#pragma unroll
        for (int mi = 0; mi < 4; ++mi) fa[mi] = *(const f16x8*)(buf + aOff + mi * 512);
#pragma unroll
        for (int ni = 0; ni < 4; ++ni) fb[ni] = *(const f16x8*)(buf + bOff + ni * 512);
    };

    f32x4 acc[4][4] = {};
    const int NT = K >> 5;                       // 64 (even; NT%4==0)

    stage(0); stage(1); stage(2);
    __builtin_amdgcn_s_waitcnt(0x0F76);          // vmcnt(6): tile 0 landed
    asm volatile("" ::: "memory");
    __builtin_amdgcn_s_barrier();
    asm volatile("" ::: "memory");

    f16x8 fA0[4], fB0[4], fA1[4], fB1[4];
    ldfrag(0, fA0, fB0);

    auto body = [&](int t, f16x8 (&ca)[4], f16x8 (&cb)[4],
                    f16x8 (&na)[4], f16x8 (&nb)[4]) {
        if (t + 1 < NT) {
            if (t + 2 < NT) __builtin_amdgcn_s_waitcnt(0x0F73);  // vmcnt(3): tile t+1 landed
            else            __builtin_amdgcn_s_waitcnt(0x0F70);  // vmcnt(0)
        }
        asm volatile("" ::: "memory");
        __builtin_amdgcn_s_barrier();
        asm volatile("" ::: "memory");
        if (t + 1 < NT) ldfrag(t + 1, na, nb);   // completes under the MFMAs below
        if (t + 3 < NT) stage(t + 3);            // overwrites buf (t-1)&3: safe post-barrier
        __builtin_amdgcn_s_setprio(1);
#pragma unroll
        for (int mi = 0; mi < 4; ++mi)
#pragma unroll
            for (int ni = 0; ni < 4; ++ni)
                acc[mi][ni] = MFMA16(ca[mi], cb[ni], acc[mi][ni]);
        __builtin_amdgcn_s_setprio(0);
    };

    for (int t = 0; t < NT; t += 2) {
        body(t,     fA0, fB0, fA1, fB1);
        body(t + 1, fA1, fB1, fA0, fB0);
    }

    if (EPI == 1) {
#pragma unroll
        for (int mi = 0; mi < 4; ++mi)
#pragma unroll
            for (int ni = 0; ni < 4; ++ni) {
                int row = m0 + wm * 64 + mi * 16 + quad * 4;
                int col = n0 + wn * 64 + ni * 16 + l16;
#pragma unroll
                for (int r = 0; r < 4; ++r)
                    Cf[(size_t)(row + r) * N + col] = acc[mi][ni][r];
            }
    } else {
        // epilogue: per-wave private 8KB restage region (bytes [0,64K), disjoint
        // from buf3 = bytes [72K,96K) which holds the final tile NT-1 (63&3==3)).
        const int which = n0 >> 11;                  // 0=q, 1=k, 2=v
        const int h0 = (n0 & 2047) >> 7;
        const int b = m0 >> 11;
        const int hw = h0 + (wn >> 1);
        const int bh = b * 16 + hw;
        const int dh0 = (wn & 1) * 64;
        const int t0 = (m0 & 2047) + wm * 64;
        u16* stg = lds_ + wave * 4096;
        const int lr = lane >> 3, lc = lane & 7;
        const float scl = (which == 0) ? 0.12751791061880135f : 1.0f;  // SCALE*log2(e)
        if (which == 2) {
            // stage transposed: row = dh_local, col = t_local
#pragma unroll
            for (int mi = 0; mi < 4; ++mi)
#pragma unroll
                for (int ni = 0; ni < 4; ++ni)
#pragma unroll
                    for (int r = 0; r < 4; ++r) {
                        int row = ni * 16 + l16;
                        int col = mi * 16 + quad * 4 + r;
                        stg[row * 64 + (((col >> 3) ^ (row & 7)) * 8) + (col & 7)] =
                            f2h(acc[mi][ni][r]);
                    }
#pragma unroll
            for (int i = 0; i < 8; ++i) {
                int row = i * 8 + lr;
                u16x8 vv = *(const u16x8*)(stg + row * 64 + ((lc ^ (row & 7)) * 8));
                *(u16x8*)(vt + ((size_t)bh * 128 + dh0 + row) * 2048 + t0 + lc * 8) = vv;
            }
        } else {
            u16* dst0 = (which == 0 ? q : kk);
            // stage row-major: row = t_local, col = dh_local
#pragma unroll
            for (int mi = 0; mi < 4; ++mi)
#pragma unroll
                for (int ni = 0; ni < 4; ++ni)
#pragma unroll
                    for (int r = 0; r < 4; ++r) {
                        int row = mi * 16 + quad * 4 + r;
                        int col = ni * 16 + l16;
                        stg[row * 64 + (((col >> 3) ^ (row & 7)) * 8) + (col & 7)] =
                            f2h(acc[mi][ni][r] * scl);
                    }
#pragma unroll
            for (int i = 0; i < 8; ++i) {
                int row = i * 8 + lr;
                u16x8 vv = *(const u16x8*)(stg + row * 64 + ((lc ^ (row & 7)) * 8));
                *(u16x8*)(dst0 + ((size_t)bh * 2048 + t0 + row) * 128 + dh0 + lc * 8) = vv;
            }
        }
    }
}

// ---------------- flash attention, causal, 128 q-rows x 64 k-cols tiles ------
// Q [BH,T,128] fp16 (pre-scaled by SCALE*log2e), K [BH,T,128] fp16,
// Vt [BH,128,T] fp16 -> Y [B,T,D] fp16
// R3 changes: (a) V-frags for k2=0 prefetched BEFORE the softmax (latency
// hides under exp/pack VALU); k2=1 V reads issue under k2=0's PV MFMAs;
// (b) s_setprio(1) around both MFMA clusters (T5, +4-7% measured on attn).
// FP contribution order into oacc unchanged (k2=0 then k2=1 per dt).
__global__ __launch_bounds__(256, 2) void flash_k(const u16* __restrict__ Q,
                                                  const u16* __restrict__ Kx,
                                                  const u16* __restrict__ Vt,
                                                  u16* __restrict__ Y) {
    __shared__ __align__(16) u16 lK0[64 * 128];
    __shared__ __align__(16) u16 lK1[64 * 128];
    __shared__ __align__(16) u16 lV0[128 * 64];
    __shared__ __align__(16) u16 lV1[128 * 64];
    __shared__ __align__(16) u16 lP[8 * 16 * 64];
    const int tid = threadIdx.x;
    const int wave = tid >> 6, lane = tid & 63;
    const int quad = lane >> 4, l16 = lane & 15;
    const int lx7 = l16 & 7;
    const int bh = blockIdx.y;
    const int qt = (blockIdx.y < 16) ? blockIdx.x : (15 - blockIdx.x);
    const int qt0 = qt * 128;

    f16x8 qf[2][4];
#pragma unroll
    for (int mi = 0; mi < 2; ++mi) {
        const u16* qrow = Q + ((size_t)bh * 2048 + qt0 + mi * 64 + wave * 16 + l16) * 128 + quad * 8;
#pragma unroll
        for (int ks = 0; ks < 4; ++ks) qf[mi][ks] = *(const f16x8*)(qrow + ks * 32);
    }

    f32x4 oacc[2][8] = {};
    float rsum[2] = {0.0f, 0.0f};
    const int qn0 = qt0 + wave * 16 + l16;
    const int qn1 = qn0 + 64;

    const u16* kgbase = Kx + (size_t)bh * 2048 * 128;
    const u16* vgbase = Vt + (size_t)bh * 128 * 2048;
    const int nkt = 2 * qt + 2;

    auto stage = [&](int kt0, u16* dK, u16* dV) {
#pragma unroll
        for (int i = 0; i < 4; ++i) {
            int row = wave * 16 + i * 4 + (lane >> 4);
            int g = (lane & 15) ^ (row & 7);
            gll16(kgbase + (size_t)(kt0 + row) * 128 + g * 8, dK + wave * 2048 + i * 512);
        }
#pragma unroll
        for (int i = 0; i < 4; ++i) {
            int row = wave * 32 + i * 8 + (lane >> 3);
            int g = (lane & 7) ^ (row & 7);
            gll16(vgbase + (size_t)row * 2048 + kt0 + g * 8, dV + wave * 2048 + i * 512);
        }
    };

    auto compute = [&](auto mode_c, const u16* bK, const u16* bV, int kt0) {
        constexpr int MODE = decltype(mode_c)::v;
        // S^T = K Q^T : A-frag = K rows (m = k-index), B-frag = Q rows (n = q)
        f32x4 sT[2][4] = {};
        __builtin_amdgcn_s_setprio(1);
#pragma unroll
        for (int mc = 0; mc < 4; ++mc)
#pragma unroll
            for (int ks = 0; ks < 4; ++ks) {
                f16x8 kb = *(const f16x8*)(bK + (mc * 16 + l16) * 128 +
                                           (((4 * ks + quad) ^ lx7) * 8));
                if (MODE != 2) sT[0][mc] = MFMA16(kb, qf[0][ks], sT[0][mc]);
                sT[1][mc] = MFMA16(kb, qf[1][ks], sT[1][mc]);
            }
        __builtin_amdgcn_s_setprio(0);

        // V prefetch (k2=0): latency hides under the softmax VALU below
        f16x8 vb0[8];
#pragma unroll
        for (int dt = 0; dt < 8; ++dt)
            vb0[dt] = *(const f16x8*)(bV + (dt * 16 + l16) * 64 + ((quad ^ lx7) * 8));

        // p = exp2(sT) (Q pre-scaled); pack pairs; b32 writes into A-layout P
#pragma unroll
        for (int mi = 0; mi < 2; ++mi) {
            if (MODE == 2 && mi == 0) continue;
            constexpr bool DIAG0 = (MODE == 1);
            constexpr bool DIAG1 = (MODE == 2);
            const bool DIAG = (mi == 0) ? DIAG0 : DIAG1;
            const int qn = (mi == 0) ? qn0 : qn1;
            u16* pw = lP + (wave * 2 + mi) * 1024 + l16 * 64 + (quad & 1) * 4;
#pragma unroll
            for (int mc = 0; mc < 4; ++mc) {
                float p0 = __builtin_exp2f(sT[mi][mc][0]);
                float p1 = __builtin_exp2f(sT[mi][mc][1]);
                float p2 = __builtin_exp2f(sT[mi][mc][2]);
                float p3 = __builtin_exp2f(sT[mi][mc][3]);
                if (DIAG) {
                    int kg = kt0 + mc * 16 + quad * 4;
                    p0 = (kg + 0 > qn) ? 0.0f : p0;
                    p1 = (kg + 1 > qn) ? 0.0f : p1;
                    p2 = (kg + 2 > qn) ? 0.0f : p2;
                    p3 = (kg + 3 > qn) ? 0.0f : p3;
                }
                rsum[mi] += (p0 + p1) + (p2 + p3);
                int gp = (((2 * mc + (quad >> 1)) ^ lx7) * 8);
                *(unsigned*)(pw + gp)     = pkh(p0, p1);
                *(unsigned*)(pw + gp + 2) = pkh(p2, p3);
            }
        }

        // P frags (same-wave DS ordering: writes above land before these reads)
        f16x8 pf0[2], pf1[2];
#pragma unroll
        for (int k2 = 0; k2 < 2; ++k2) {
            if (MODE != 2)
                pf0[k2] = *(const f16x8*)(lP + (wave * 2 + 0) * 1024 + l16 * 64 +
                                          (((4 * k2 + quad) ^ lx7) * 8));
            pf1[k2] = *(const f16x8*)(lP + (wave * 2 + 1) * 1024 + l16 * 64 +
                                      (((4 * k2 + quad) ^ lx7) * 8));
        }
        // k2=1 V reads issue now, complete under k2=0's MFMAs
        f16x8 vb1[8];
#pragma unroll
        for (int dt = 0; dt < 8; ++dt)
            vb1[dt] = *(const f16x8*)(bV + (dt * 16 + l16) * 64 + (((4 + quad) ^ lx7) * 8));

        __builtin_amdgcn_s_setprio(1);
#pragma unroll
        for (int dt = 0; dt < 8; ++dt) {
            if (MODE != 2) oacc[0][dt] = MFMA16(pf0[0], vb0[dt], oacc[0][dt]);
            oacc[1][dt] = MFMA16(pf1[0], vb0[dt], oacc[1][dt]);
        }
#pragma unroll
        for (int dt = 0; dt < 8; ++dt) {
            if (MODE != 2) oacc[0][dt] = MFMA16(pf0[1], vb1[dt], oacc[0][dt]);
            oacc[1][dt] = MFMA16(pf1[1], vb1[dt], oacc[1][dt]);
        }
        __builtin_amdgcn_s_setprio(0);
    };

    stage(0, lK0, lV0);
    for (int kt = 0; kt < nkt; ++kt) {
        const int kt0 = kt * 64;
        if (kt + 1 < nkt) {
            if ((kt & 1) == 0) stage(kt0 + 64, lK1, lV1);
            else               stage(kt0 + 64, lK0, lV0);
            asm volatile("" ::: "memory");
            __builtin_amdgcn_s_waitcnt(0x0F78);   // vmcnt(8)
        } else {
            asm volatile("" ::: "memory");
            __builtin_amdgcn_s_waitcnt(0x0F70);   // vmcnt(0)
        }
        __builtin_amdgcn_s_barrier();
        asm volatile("" ::: "memory");
        const u16* bK = (kt & 1) ? lK1 : lK0;
        const u16* bV = (kt & 1) ? lV1 : lV0;
        if (kt < 2 * qt)       compute(ic<0>{}, bK, bV, kt0);
        else if (kt == 2 * qt) compute(ic<1>{}, bK, bV, kt0);
        else                   compute(ic<2>{}, bK, bV, kt0);
        asm volatile("" ::: "memory");
        __builtin_amdgcn_s_barrier();
        asm volatile("" ::: "memory");
    }

    float* rb = (float*)(lP + wave * 1024);
#pragma unroll
    for (int mi = 0; mi < 2; ++mi) {
        float rs = rsum[mi];
        rs += __shfl_xor(rs, 16);
        rs += __shfl_xor(rs, 32);
        if (quad == 0) rb[mi * 16 + l16] = rs;
    }
    const int b = bh >> 4, h = bh & 15;
#pragma unroll
    for (int mi = 0; mi < 2; ++mi) {
        f32x4 rsv = *(const f32x4*)(rb + mi * 16 + quad * 4);
#pragma unroll
        for (int r = 0; r < 4; ++r) {
            float inv = 1.0f / rsv[r];
            int t = qt0 + mi * 64 + wave * 16 + quad * 4 + r;
            u16* yr = Y + ((size_t)b * 2048 + t) * 2048 + h * 128;
#pragma unroll
            for (int dt = 0; dt < 8; ++dt) yr[dt * 16 + l16] = f2h(oacc[mi][dt][r] * inv);
        }
    }
}

extern "C" void kernel_launch(void* const* d_in, const int* in_sizes, int n_in,
                              void* d_out, int out_size, void* d_ws, size_t ws_size,
                              hipStream_t stream) {
    const float* x    = (const float*)d_in[0];
    const float* nw   = (const float*)d_in[1];
    const float* wqkv = (const float*)d_in[2];
    const float* wout = (const float*)d_in[3];
    float* out = (float*)d_out;

    // workspace layout (u16 elements)
    u16* ws = (u16*)d_ws;
    u16* xn      = ws;                      //  4096*2048        = 8388608
    u16* wqkv_b  = xn + 8388608;            //  6144*2048        = 12582912
    u16* wout_b  = wqkv_b + 12582912;       //  2048*2048        = 4194304
    u16* q       = wout_b + 4194304;        //  [32][2048][128]  = 8388608
    u16* kk      = q + 8388608;             //  [32][2048][128]
    u16* vt      = kk + 8388608;            //  [32][128][2048]
    u16* y       = vt + 8388608;            //  [4096][2048]
    // total 58,720,256 u16 = 112 MB

    prep_k<<<20480, 256, 0, stream>>>(x, nw, xn, wqkv, wqkv_b, wout, wqkv ? wout_b : wout_b);

    gemm_dp<0><<<768, 512, 0, stream>>>(xn, wqkv_b, 2048, 6144, nullptr, q, kk, vt);

    dim3 gf(16, 32);
    flash_k<<<gf, 256, 0, stream>>>(q, kk, vt, y);

    gemm_dp<1><<<256, 512, 0, stream>>>(y, wout_b, 2048, 2048, out, nullptr, nullptr, nullptr);
}

// Round 7
// 375.125 us; speedup vs baseline: 1.0191x; 1.0191x over previous
//
#include <hip/hip_runtime.h>

typedef unsigned short u16;
typedef _Float16 f16;
typedef f16    f16x8  __attribute__((ext_vector_type(8)));
typedef float  f32x4  __attribute__((ext_vector_type(4)));
typedef u16    u16x4  __attribute__((ext_vector_type(4)));
typedef u16    u16x8  __attribute__((ext_vector_type(8)));

#define MFMA16(a, b, c) __builtin_amdgcn_mfma_f32_16x16x32_f16(a, b, c, 0, 0, 0)

template <int V> struct ic { static constexpr int v = V; };

// fp32 -> fp16 RNE (v_cvt_f16_f32), bit pattern as u16
__device__ __forceinline__ u16 f2h(float f) {
    f16 h = (f16)f;
    return __builtin_bit_cast(u16, h);
}

// pack two fp32 -> fp16x2 in one u32 (2x v_cvt_f16_f32 + v_pack_b32_f16)
__device__ __forceinline__ unsigned pkh(float a, float b) {
    union { f16 h[2]; unsigned u; } c;
    c.h[0] = (f16)a;
    c.h[1] = (f16)b;
    return c.u;
}

// async global->LDS, 16B per lane; LDS dest is wave-uniform base + lane*16
__device__ __forceinline__ void gll16(const void* g, void* l) {
    __builtin_amdgcn_global_load_lds((__attribute__((address_space(1))) void*)(void*)(g),
                                     (__attribute__((address_space(3))) void*)(l), 16, 0, 0);
}

// waitcnt immediates (gfx9 encoding: vmcnt[3:0]|[15:14], expcnt[6:4], lgkm[11:8])
#define WC_VM3_LG0  0x0073   // vmcnt(3)  + lgkmcnt(0)
#define WC_VM0_LG0  0x0070   // vmcnt(0)  + lgkmcnt(0)
#define WC_VM8_LG0  0x0078   // vmcnt(8)  + lgkmcnt(0)
#define WC_LG0      0xC07F   // lgkmcnt(0) only
#define WC_VM6      0x0F76   // vmcnt(6)

// ------------- fused prep: weight casts fp32->fp16 + RMSNorm ----------------
// blocks [0,4096): RMSNorm rows; [4096, 4096+16384): weight cast chunks
__global__ __launch_bounds__(256) void prep_k(const float* __restrict__ x,
                                              const float* __restrict__ w,
                                              u16* __restrict__ xn,
                                              const float* __restrict__ wq,
                                              u16* __restrict__ oq,
                                              const float* __restrict__ wo,
                                              u16* __restrict__ oo) {
    const int bid = blockIdx.x;
    if (bid >= 4096) {
        const int cb = bid - 4096;
        const float* in;
        u16* out;
        size_t i;
        if (cb < 12288) { in = wq; out = oq; i = ((size_t)cb * 256 + threadIdx.x) * 4; }
        else            { in = wo; out = oo; i = ((size_t)(cb - 12288) * 256 + threadIdx.x) * 4; }
        float4 v = *(const float4*)(in + i);
        u16x4 o;
        o.x = f2h(v.x); o.y = f2h(v.y); o.z = f2h(v.z); o.w = f2h(v.w);
        *(u16x4*)(out + i) = o;
        return;
    }
    const int row = bid;
    const float* xr = x + (size_t)row * 2048;
    const int base = threadIdx.x * 8;
    float4 v0 = *(const float4*)(xr + base);
    float4 v1 = *(const float4*)(xr + base + 4);
    float ss = v0.x * v0.x + v0.y * v0.y + v0.z * v0.z + v0.w * v0.w +
               v1.x * v1.x + v1.y * v1.y + v1.z * v1.z + v1.w * v1.w;
#pragma unroll
    for (int off = 32; off >= 1; off >>= 1) ss += __shfl_xor(ss, off);
    __shared__ float red[4];
    const int wave = threadIdx.x >> 6, lane = threadIdx.x & 63;
    if (lane == 0) red[wave] = ss;
    __syncthreads();
    float tot = red[0] + red[1] + red[2] + red[3];
    float sc = rsqrtf(tot * (1.0f / 2048.0f) + 1e-6f);
    const float* wp = w + base;
    u16x4 a, b;
    a.x = f2h(v0.x * sc * wp[0]); a.y = f2h(v0.y * sc * wp[1]);
    a.z = f2h(v0.z * sc * wp[2]); a.w = f2h(v0.w * sc * wp[3]);
    b.x = f2h(v1.x * sc * wp[4]); b.y = f2h(v1.y * sc * wp[5]);
    b.z = f2h(v1.z * sc * wp[6]); b.w = f2h(v1.w * sc * wp[7]);
    u16* o = xn + (size_t)row * 2048 + base;
    *(u16x4*)(o)     = a;
    *(u16x4*)(o + 4) = b;
}

// ------- deep-pipe GEMM: 128x256 tile, single barrier per K-tile ------------
// C = A[M,K] * B[N,K]^T, fp16 in. 512 threads = 8 waves (2M x 4N), per-wave
// 64x64 (acc[4][4]). BK=32, quad-buffered LDS 4 x 24KB = 96KB, 1 block/CU.
// sched_barrier(0) pins {ldfrag(t+1) + stage(t+3)} issue BEFORE the MFMA
// cluster: the 8 ds_reads drain on the LDS pipe UNDER the 16 MFMAs.
// R7 RACE FIX (R5/R6 failures): MFMA(t) is register-only; the scheduler may
// defer it — and the lgkm wait for ldfrag(t)'s ds_reads, inserted at first
// use — past barrier(t+1). Those in-flight ds_reads of buf t&3 then race
// with stage(t+4)'s global_load_lds writes to the SAME buf issued by waves
// already past the barrier (in-flight ds_read samples LDS late -> returns
// tile t+4 data). INVARIANT enforced now: no ds-op in flight at ANY barrier —
// every pre-barrier waitcnt includes lgkmcnt(0), followed by sched_barrier(0)
// so nothing hoists above it. The lgkm wait is free: 8 ds_reads drain in
// ~100cy under the ~620cy MFMA cluster.
// Gate accounting: in-flight at gate(t) = tiles {t+1,t+2} (3 loads each);
// vmcnt(3) drains t+1; tail t=NT-2 -> vmcnt(0); t=NT-1 -> lgkm(0) only.
// Swizzle identical to verified kernels (granule p^((r>>1)&3), gsrc, fofs).
// EPI 0: q/k/v via per-wave XOR-swizzled [64][64] restage, post-loop barrier.
// EPI 1: fp32 row-major C[M,N] direct (global-only epilogue, no hazard).
template <int EPI>
__global__ __launch_bounds__(512, 2) void gemm_dp(const u16* __restrict__ A,
                                                  const u16* __restrict__ B,
                                                  int K, int N,
                                                  float* __restrict__ Cf,
                                                  u16* __restrict__ q,
                                                  u16* __restrict__ kk,
                                                  u16* __restrict__ vt) {
    __shared__ __align__(16) u16 lds_[49152];   // 96KB: buf b at b*12288; A [0,4096) B [4096,12288)
    const int tid = threadIdx.x;
    const int wave = tid >> 6, lane = tid & 63;
    const int wm = wave >> 2, wn = wave & 3;
    const int quad = lane >> 4, l16 = lane & 15;

    const int bid = blockIdx.x;
    const int xcd = bid & 7, ci = bid >> 3;
    int bm, bn;
    if (EPI == 0) { bm = ci & 31; bn = xcd * 3 + (ci >> 5); }   // 32 x 24 grid, 768 blocks
    else          { bm = ci;      bn = xcd; }                   // 32 x 8 grid, 256 blocks
    const int m0 = bm * 128, n0 = bn * 256;

    // ---- staging: 512 threads; rows tid>>2, granule-permuted source --------
    const int gsrc = (tid & 3) ^ ((tid >> 3) & 3);
    const u16* Ag = A + (size_t)(m0 + (tid >> 2)) * K + gsrc * 8;
    const u16* Bg = B + (size_t)(n0 + (tid >> 2)) * K + gsrc * 8;
    u16* ldsW = lds_ + wave * 512;

    auto stage = [&](int t) {                    // 3 loads: A, B-lo, B-hi
        u16* d = ldsW + (t & 3) * 12288;
        const u16* ga = Ag + t * 32;
        const u16* gb = Bg + t * 32;
        gll16(ga, d);
        gll16(gb, d + 4096);
        gll16(gb + (size_t)128 * K, d + 8192);
    };

    // ---- fragment read offsets (u16 units) ----
    const int fofs = (quad ^ ((l16 >> 1) & 3)) * 8;
    const int aOff = (wm * 64 + l16) * 32 + fofs;
    const int bOff = 4096 + (wn * 64 + l16) * 32 + fofs;

    auto ldfrag = [&](int t, f16x8 (&fa)[4], f16x8 (&fb)[4]) {
        const u16* buf = lds_ + (t & 3) * 12288;
#pragma unroll
        for (int mi = 0; mi < 4; ++mi) fa[mi] = *(const f16x8*)(buf + aOff + mi * 512);
#pragma unroll
        for (int ni = 0; ni < 4; ++ni) fb[ni] = *(const f16x8*)(buf + bOff + ni * 512);
    };

    f32x4 acc[4][4] = {};
    const int NT = K >> 5;                       // 64 (even; NT%4==0)

    stage(0); stage(1); stage(2);
    __builtin_amdgcn_s_waitcnt(WC_VM6);          // vmcnt(6): tile 0 landed
    asm volatile("" ::: "memory");
    __builtin_amdgcn_s_barrier();
    asm volatile("" ::: "memory");

    f16x8 fA0[4], fB0[4], fA1[4], fB1[4];
    ldfrag(0, fA0, fB0);

    auto body = [&](int t, f16x8 (&ca)[4], f16x8 (&cb)[4],
                    f16x8 (&na)[4], f16x8 (&nb)[4]) {
        // pre-barrier: drain own vm (next tile landed) AND lgkm (no ds-op of
        // mine in flight when I arrive at the barrier — see R7 RACE FIX).
        if (t + 1 < NT) {
            if (t + 2 < NT) __builtin_amdgcn_s_waitcnt(WC_VM3_LG0);
            else            __builtin_amdgcn_s_waitcnt(WC_VM0_LG0);
        } else {
            __builtin_amdgcn_s_waitcnt(WC_LG0);
        }
        __builtin_amdgcn_sched_barrier(0);       // nothing hoists above the wait
        asm volatile("" ::: "memory");
        __builtin_amdgcn_s_barrier();
        asm volatile("" ::: "memory");
        if (t + 1 < NT) ldfrag(t + 1, na, nb);   // 8 ds_read: drain under MFMAs below
        if (t + 3 < NT) stage(t + 3);            // overwrites buf (t-1)&3: safe post-barrier
        __builtin_amdgcn_sched_barrier(0);       // pin: loads issued BEFORE the MFMA cluster
        __builtin_amdgcn_s_setprio(1);
#pragma unroll
        for (int mi = 0; mi < 4; ++mi)
#pragma unroll
            for (int ni = 0; ni < 4; ++ni)
                acc[mi][ni] = MFMA16(ca[mi], cb[ni], acc[mi][ni]);
        __builtin_amdgcn_s_setprio(0);
    };

    for (int t = 0; t < NT; t += 2) {
        body(t,     fA0, fB0, fA1, fB1);
        body(t + 1, fA1, fB1, fA0, fB0);
    }

    if (EPI == 1) {
#pragma unroll
        for (int mi = 0; mi < 4; ++mi)
#pragma unroll
            for (int ni = 0; ni < 4; ++ni) {
                int row = m0 + wm * 64 + mi * 16 + quad * 4;
                int col = n0 + wn * 64 + ni * 16 + l16;
#pragma unroll
                for (int r = 0; r < 4; ++r)
                    Cf[(size_t)(row + r) * N + col] = acc[mi][ni][r];
            }
    } else {
        // loop->epilogue: wait out any of MY ds-ops, then barrier so no wave
        // overwrites LDS while another's reads could still be in flight.
        __builtin_amdgcn_s_waitcnt(WC_LG0);
        __builtin_amdgcn_sched_barrier(0);
        asm volatile("" ::: "memory");
        __builtin_amdgcn_s_barrier();
        asm volatile("" ::: "memory");
        // epilogue: per-wave private 8KB restage region (bytes [0,64K), disjoint
        // from buf3 = bytes [72K,96K) which holds the final tile NT-1 (63&3==3)).
        const int which = n0 >> 11;                  // 0=q, 1=k, 2=v
        const int h0 = (n0 & 2047) >> 7;
        const int b = m0 >> 11;
        const int hw = h0 + (wn >> 1);
        const int bh = b * 16 + hw;
        const int dh0 = (wn & 1) * 64;
        const int t0 = (m0 & 2047) + wm * 64;
        u16* stg = lds_ + wave * 4096;
        const int lr = lane >> 3, lc = lane & 7;
        const float scl = (which == 0) ? 0.12751791061880135f : 1.0f;  // SCALE*log2(e)
        if (which == 2) {
            // stage transposed: row = dh_local, col = t_local
#pragma unroll
            for (int mi = 0; mi < 4; ++mi)
#pragma unroll
                for (int ni = 0; ni < 4; ++ni)
#pragma unroll
                    for (int r = 0; r < 4; ++r) {
                        int row = ni * 16 + l16;
                        int col = mi * 16 + quad * 4 + r;
                        stg[row * 64 + (((col >> 3) ^ (row & 7)) * 8) + (col & 7)] =
                            f2h(acc[mi][ni][r]);
                    }
#pragma unroll
            for (int i = 0; i < 8; ++i) {
                int row = i * 8 + lr;
                u16x8 vv = *(const u16x8*)(stg + row * 64 + ((lc ^ (row & 7)) * 8));
                *(u16x8*)(vt + ((size_t)bh * 128 + dh0 + row) * 2048 + t0 + lc * 8) = vv;
            }
        } else {
            u16* dst0 = (which == 0 ? q : kk);
            // stage row-major: row = t_local, col = dh_local
#pragma unroll
            for (int mi = 0; mi < 4; ++mi)
#pragma unroll
                for (int ni = 0; ni < 4; ++ni)
#pragma unroll
                    for (int r = 0; r < 4; ++r) {
                        int row = mi * 16 + quad * 4 + r;
                        int col = ni * 16 + l16;
                        stg[row * 64 + (((col >> 3) ^ (row & 7)) * 8) + (col & 7)] =
                            f2h(acc[mi][ni][r] * scl);
                    }
#pragma unroll
            for (int i = 0; i < 8; ++i) {
                int row = i * 8 + lr;
                u16x8 vv = *(const u16x8*)(stg + row * 64 + ((lc ^ (row & 7)) * 8));
                *(u16x8*)(dst0 + ((size_t)bh * 2048 + t0 + row) * 128 + dh0 + lc * 8) = vv;
            }
        }
    }
}

// ---------------- flash attention, causal, 128 q-rows x 64 k-cols tiles ------
// Q [BH,T,128] fp16 (pre-scaled by SCALE*log2e), K [BH,T,128] fp16,
// Vt [BH,128,T] fp16 -> Y [B,T,D] fp16  (R1-verified structure)
// R7: same no-ds-in-flight-at-barrier invariant as gemm_dp — lgkm(0) merged
// into the staging gate, and lgkm(0)+sched_barrier before the post-compute
// barrier (an MFMA consuming vb/pf could otherwise sink past it, leaving
// ds_reads of buf kt&1 in flight while stage(kt+2) overwrites that buffer).
__global__ __launch_bounds__(256, 2) void flash_k(const u16* __restrict__ Q,
                                                  const u16* __restrict__ Kx,
                                                  const u16* __restrict__ Vt,
                                                  u16* __restrict__ Y) {
    __shared__ __align__(16) u16 lK0[64 * 128];
    __shared__ __align__(16) u16 lK1[64 * 128];
    __shared__ __align__(16) u16 lV0[128 * 64];
    __shared__ __align__(16) u16 lV1[128 * 64];
    __shared__ __align__(16) u16 lP[8 * 16 * 64];
    const int tid = threadIdx.x;
    const int wave = tid >> 6, lane = tid & 63;
    const int quad = lane >> 4, l16 = lane & 15;
    const int lx7 = l16 & 7;
    const int bh = blockIdx.y;
    const int qt = (blockIdx.y < 16) ? blockIdx.x : (15 - blockIdx.x);
    const int qt0 = qt * 128;

    f16x8 qf[2][4];
#pragma unroll
    for (int mi = 0; mi < 2; ++mi) {
        const u16* qrow = Q + ((size_t)bh * 2048 + qt0 + mi * 64 + wave * 16 + l16) * 128 + quad * 8;
#pragma unroll
        for (int ks = 0; ks < 4; ++ks) qf[mi][ks] = *(const f16x8*)(qrow + ks * 32);
    }

    f32x4 oacc[2][8] = {};
    float rsum[2] = {0.0f, 0.0f};
    const int qn0 = qt0 + wave * 16 + l16;
    const int qn1 = qn0 + 64;

    const u16* kgbase = Kx + (size_t)bh * 2048 * 128;
    const u16* vgbase = Vt + (size_t)bh * 128 * 2048;
    const int nkt = 2 * qt + 2;

    auto stage = [&](int kt0, u16* dK, u16* dV) {
#pragma unroll
        for (int i = 0; i < 4; ++i) {
            int row = wave * 16 + i * 4 + (lane >> 4);
            int g = (lane & 15) ^ (row & 7);
            gll16(kgbase + (size_t)(kt0 + row) * 128 + g * 8, dK + wave * 2048 + i * 512);
        }
#pragma unroll
        for (int i = 0; i < 4; ++i) {
            int row = wave * 32 + i * 8 + (lane >> 3);
            int g = (lane & 7) ^ (row & 7);
            gll16(vgbase + (size_t)row * 2048 + kt0 + g * 8, dV + wave * 2048 + i * 512);
        }
    };

    auto compute = [&](auto mode_c, const u16* bK, const u16* bV, int kt0) {
        constexpr int MODE = decltype(mode_c)::v;
        f32x4 sT[2][4] = {};
#pragma unroll
        for (int mc = 0; mc < 4; ++mc)
#pragma unroll
            for (int ks = 0; ks < 4; ++ks) {
                f16x8 kb = *(const f16x8*)(bK + (mc * 16 + l16) * 128 +
                                           (((4 * ks + quad) ^ lx7) * 8));
                if (MODE != 2) sT[0][mc] = MFMA16(kb, qf[0][ks], sT[0][mc]);
                sT[1][mc] = MFMA16(kb, qf[1][ks], sT[1][mc]);
            }

#pragma unroll
        for (int mi = 0; mi < 2; ++mi) {
            if (MODE == 2 && mi == 0) continue;
            constexpr bool DIAG0 = (MODE == 1);
            constexpr bool DIAG1 = (MODE == 2);
            const bool DIAG = (mi == 0) ? DIAG0 : DIAG1;
            const int qn = (mi == 0) ? qn0 : qn1;
            u16* pw = lP + (wave * 2 + mi) * 1024 + l16 * 64 + (quad & 1) * 4;
#pragma unroll
            for (int mc = 0; mc < 4; ++mc) {
                float p0 = __builtin_exp2f(sT[mi][mc][0]);
                float p1 = __builtin_exp2f(sT[mi][mc][1]);
                float p2 = __builtin_exp2f(sT[mi][mc][2]);
                float p3 = __builtin_exp2f(sT[mi][mc][3]);
                if (DIAG) {
                    int kg = kt0 + mc * 16 + quad * 4;
                    p0 = (kg + 0 > qn) ? 0.0f : p0;
                    p1 = (kg + 1 > qn) ? 0.0f : p1;
                    p2 = (kg + 2 > qn) ? 0.0f : p2;
                    p3 = (kg + 3 > qn) ? 0.0f : p3;
                }
                rsum[mi] += (p0 + p1) + (p2 + p3);
                int gp = (((2 * mc + (quad >> 1)) ^ lx7) * 8);
                *(unsigned*)(pw + gp)     = pkh(p0, p1);
                *(unsigned*)(pw + gp + 2) = pkh(p2, p3);
            }
        }

        f16x8 pf0[2], pf1[2];
#pragma unroll
        for (int k2 = 0; k2 < 2; ++k2) {
            if (MODE != 2)
                pf0[k2] = *(const f16x8*)(lP + (wave * 2 + 0) * 1024 + l16 * 64 +
                                          (((4 * k2 + quad) ^ lx7) * 8));
            pf1[k2] = *(const f16x8*)(lP + (wave * 2 + 1) * 1024 + l16 * 64 +
                                      (((4 * k2 + quad) ^ lx7) * 8));
        }
#pragma unroll
        for (int dt = 0; dt < 8; ++dt)
#pragma unroll
            for (int k2 = 0; k2 < 2; ++k2) {
                f16x8 vb = *(const f16x8*)(bV + (dt * 16 + l16) * 64 +
                                           (((4 * k2 + quad) ^ lx7) * 8));
                if (MODE != 2) oacc[0][dt] = MFMA16(pf0[k2], vb, oacc[0][dt]);
                oacc[1][dt] = MFMA16(pf1[k2], vb, oacc[1][dt]);
            }
    };

    stage(0, lK0, lV0);
    for (int kt = 0; kt < nkt; ++kt) {
        const int kt0 = kt * 64;
        if (kt + 1 < nkt) {
            if ((kt & 1) == 0) stage(kt0 + 64, lK1, lV1);
            else               stage(kt0 + 64, lK0, lV0);
            __builtin_amdgcn_s_waitcnt(WC_VM8_LG0);   // vmcnt(8)+lgkm(0)
        } else {
            __builtin_amdgcn_s_waitcnt(WC_VM0_LG0);   // vmcnt(0)+lgkm(0)
        }
        __builtin_amdgcn_sched_barrier(0);
        asm volatile("" ::: "memory");
        __builtin_amdgcn_s_barrier();
        asm volatile("" ::: "memory");
        const u16* bK = (kt & 1) ? lK1 : lK0;
        const u16* bV = (kt & 1) ? lV1 : lV0;
        if (kt < 2 * qt)       compute(ic<0>{}, bK, bV, kt0);
        else if (kt == 2 * qt) compute(ic<1>{}, bK, bV, kt0);
        else                   compute(ic<2>{}, bK, bV, kt0);
        // no ds-op in flight when crossing this barrier (next iter overwrites
        // buf kt&1 right after it)
        __builtin_amdgcn_s_waitcnt(WC_LG0);
        __builtin_amdgcn_sched_barrier(0);
        asm volatile("" ::: "memory");
        __builtin_amdgcn_s_barrier();
        asm volatile("" ::: "memory");
    }

    float* rb = (float*)(lP + wave * 1024);
#pragma unroll
    for (int mi = 0; mi < 2; ++mi) {
        float rs = rsum[mi];
        rs += __shfl_xor(rs, 16);
        rs += __shfl_xor(rs, 32);
        if (quad == 0) rb[mi * 16 + l16] = rs;
    }
    const int b = bh >> 4, h = bh & 15;
#pragma unroll
    for (int mi = 0; mi < 2; ++mi) {
        f32x4 rsv = *(const f32x4*)(rb + mi * 16 + quad * 4);
#pragma unroll
        for (int r = 0; r < 4; ++r) {
            float inv = 1.0f / rsv[r];
            int t = qt0 + mi * 64 + wave * 16 + quad * 4 + r;
            u16* yr = Y + ((size_t)b * 2048 + t) * 2048 + h * 128;
#pragma unroll
            for (int dt = 0; dt < 8; ++dt) yr[dt * 16 + l16] = f2h(oacc[mi][dt][r] * inv);
        }
    }
}

extern "C" void kernel_launch(void* const* d_in, const int* in_sizes, int n_in,
                              void* d_out, int out_size, void* d_ws, size_t ws_size,
                              hipStream_t stream) {
    const float* x    = (const float*)d_in[0];
    const float* nw   = (const float*)d_in[1];
    const float* wqkv = (const float*)d_in[2];
    const float* wout = (const float*)d_in[3];
    float* out = (float*)d_out;

    // workspace layout (u16 elements)
    u16* ws = (u16*)d_ws;
    u16* xn      = ws;                      //  4096*2048        = 8388608
    u16* wqkv_b  = xn + 8388608;            //  6144*2048        = 12582912
    u16* wout_b  = wqkv_b + 12582912;       //  2048*2048        = 4194304
    u16* q       = wout_b + 4194304;        //  [32][2048][128]  = 8388608
    u16* kk      = q + 8388608;             //  [32][2048][128]
    u16* vt      = kk + 8388608;            //  [32][128][2048]
    u16* y       = vt + 8388608;            //  [4096][2048]
    // total 58,720,256 u16 = 112 MB

    prep_k<<<20480, 256, 0, stream>>>(x, nw, xn, wqkv, wqkv_b, wout, wout_b);

    gemm_dp<0><<<768, 512, 0, stream>>>(xn, wqkv_b, 2048, 6144, nullptr, q, kk, vt);

    dim3 gf(16, 32);
    flash_k<<<gf, 256, 0, stream>>>(q, kk, vt, y);

    gemm_dp<1><<<256, 512, 0, stream>>>(y, wout_b, 2048, 2048, out, nullptr, nullptr, nullptr);
}